// Round 6
// baseline (160.545 us; speedup 1.0000x reference)
//
#include <hip/hip_runtime.h>
#include <hip/hip_bf16.h>

// HT layer via bf16 32x32x16 MFMA.
//   Y[b] = sum_p A_p(64x64) @ X_b(64x64) @ W_p(64x64) + bias
// Step A: T^T[kl][ac] = sum_ij X^T[kl][ij] * A_p^T[ij][ac]   (A=X^T frag, B=AF)
// Step B: Y[ac][de]  += sum_kl T[ac][kl]  * W_p[kl][de]      (A=tb repack, B=WF)
// mfma_f32_32x32x16_bf16 layouts:
//   A: A[m=lane&31][k=(lane>>5)*8+j]   B: B[k=(lane>>5)*8+j][n=lane&31]
//   C/D: col=lane&31, row=(reg&3)+8*(reg>>2)+4*(lane>>5)
// Step-A C/D -> step-B A-operand repack: 8 v_cvt_pk_bf16_f32 +
// 4 v_permlane32_swap per tile, fully in-register (proven rounds 1-5).
//
// Round-6 structure (phase-decoupling):
//   4-wave blocks (1 batch/wave), grid 1024. LDS = AF(64K)+bias(16K) = 80KB
//   -> EXACTLY 2 blocks/CU. One barrier at block start; p-loop has ZERO
//   barriers and zero cross-wave coupling: AF from LDS, WF streamed from L2
//   into registers (8 dwordx4/p, issued at p-top, first use ~350cy later
//   behind 8 step-A MFMAs + 2 repacks -> L2 latency covered). Independent
//   staggered blocks overlap read/compute/write phases across the CU instead
//   of device-wide lockstep (rounds 0/2/5 all converged to 50-56us with
//   barrier-coupled phases; no pipe above 26%).
// Register discipline (round-3/4 lesson: >128 arch VGPRs => scratch spill,
// +96MB WRITE_SIZE): xr[64] dies before the p-loop; p-loop set = xf 32 +
// af 32 + wf 32 + tb 16 + tmp ~20 => ~130 VGPR, acc 64 + t 16 AGPR.

typedef short bf16x8 __attribute__((ext_vector_type(8)));
typedef float f32x16 __attribute__((ext_vector_type(16)));

union Frag8 {
    bf16x8 v;
    unsigned int u4[4];
};

static __device__ __forceinline__ unsigned int pkbf(float a, float b) {
    // v_cvt_pk_bf16_f32 on gfx950 (RNE), a -> low 16, b -> high 16
    __hip_bfloat162 h = __float22bfloat162_rn(float2{a, b});
    return *reinterpret_cast<unsigned int*>(&h);
}

// ---------------------------------------------------------------------------
// Precompute bf16 fragments of A_p^T (step-A B-operand) and W_p (step-B
// B-operand). One block per (isW, p); two-stage contraction in LDS.
// Layout: frags[isW][p(8)][t(2)][kc(4)][lane(64)][j(8)] bf16, 64KB each half.
//   contraction index k = kc*16 + (lane>>5)*8 + j   (ij for AF, kl for WF)
//   other index       n = t*32 + (lane&31)          (ac for AF, de for WF)
// AF element = WL[ij][ac][p],  WF element = WR[kl][de][p]
// ---------------------------------------------------------------------------
__global__ __launch_bounds__(256) void ht_precompute(
        const float* __restrict__ F0, const float* __restrict__ F1,
        const float* __restrict__ F2, const float* __restrict__ F3,
        const float* __restrict__ CL, const float* __restrict__ CR,
        unsigned short* __restrict__ frags) {
    __shared__ float sFa[512], sFb[512], sC[512], sG[512];
    const int isW = blockIdx.x >> 3;
    const int p   = blockIdx.x & 7;
    const float* Fa = isW ? F2 : F0;   // (in, out, rank) = 8x8x8
    const float* Fb = isW ? F3 : F1;
    const float* C  = isW ? CR : CL;   // (r, s, p) = 8x8x8
    const int tid = threadIdx.x;

    for (int u = tid; u < 512; u += 256) {
        sFa[u] = Fa[u]; sFb[u] = Fb[u]; sC[u] = C[u];
    }
    __syncthreads();

    // stage 1: G[r][jc] = sum_s Fb[jc*8+s] * C[(r*8+s)*8+p]   (512 entries)
#pragma unroll
    for (int e = 0; e < 2; ++e) {
        int u = tid + e * 256;
        int r = u >> 6, jc = u & 63;
        float acc = 0.f;
#pragma unroll
        for (int s = 0; s < 8; ++s)
            acc += sFb[jc * 8 + s] * sC[(r * 8 + s) * 8 + p];
        sG[u] = acc;   // sG[r*64 + jc]
    }
    __syncthreads();

    // stage 2: out[k=i1*8+j][n] = sum_r Fa[(i1*8+a)*8+r] * G[r][j*8+c]
#pragma unroll
    for (int e = 0; e < 2; ++e) {
        int g  = tid + e * 256;
        int i1 = g >> 6, n = g & 63;
        int a  = n >> 3, c = n & 7;
        float fa[8];
#pragma unroll
        for (int r = 0; r < 8; ++r) fa[r] = sFa[(i1 * 8 + a) * 8 + r];
        unsigned int pk[4];
#pragma unroll
        for (int jp = 0; jp < 4; ++jp) {
            float o0 = 0.f, o1 = 0.f;
#pragma unroll
            for (int r = 0; r < 8; ++r) {
                o0 += fa[r] * sG[r * 64 + (2 * jp) * 8 + c];
                o1 += fa[r] * sG[r * 64 + (2 * jp + 1) * 8 + c];
            }
            pk[jp] = pkbf(o0, o1);
        }
        int t = n >> 5, kc = i1 >> 1, lane_ = (i1 & 1) * 32 + (n & 31);
        unsigned int* dst = (unsigned int*)(frags + (size_t)isW * 32768 +
                                            ((((p * 2 + t) * 4 + kc) << 6) + lane_) * 8);
        *(uint4*)dst = uint4{pk[0], pk[1], pk[2], pk[3]};
    }
}

__global__ __launch_bounds__(256) void ht_main(const float* __restrict__ x,
                                               const unsigned short* __restrict__ frags,
                                               const float* __restrict__ bias,
                                               float* __restrict__ out) {
    // LDS: [0,64K) AF all p | [64K,80K) bias  -> 80KB, exactly 2 blocks/CU
    __shared__ __align__(16) char smem[81920];
    const int tid  = threadIdx.x;
    const int lane = tid & 63;
    const int w    = __builtin_amdgcn_readfirstlane(tid >> 6);  // wave 0..3
    const int l31  = lane & 31;
    const int hi   = lane >> 5;
    const int b    = blockIdx.x * 4 + w;                        // 1 batch/wave

    // ---- issue x loads first (oldest in vmcnt; drain under the staging wait)
    float xr[64];   // xr[(rb*4+kc)*8 + j] = X^T[kl=rb*32+l31][ij=kc*16+hi*8+j]
    {
        const float* xb = x + ((size_t)b << 12);
#pragma unroll
        for (int rb = 0; rb < 2; ++rb)
#pragma unroll
            for (int kc = 0; kc < 4; ++kc)
#pragma unroll
                for (int j = 0; j < 8; ++j)
                    xr[(rb * 4 + kc) * 8 + j] = xb[(kc * 16 + hi * 8 + j) * 64 + rb * 32 + l31];
    }
    // ---- stage AF (64KB) + bias (16KB) into LDS, once per block
#pragma unroll
    for (int r = 0; r < 16; ++r)
        __builtin_amdgcn_global_load_lds(
            (const __attribute__((address_space(1))) void*)((const char*)frags + r * 4096 + tid * 16),
            (__attribute__((address_space(3))) void*)(smem + r * 4096 + tid * 16), 16, 0, 0);
#pragma unroll
    for (int r = 0; r < 4; ++r)
        __builtin_amdgcn_global_load_lds(
            (const __attribute__((address_space(1))) void*)((const char*)bias + r * 4096 + tid * 16),
            (__attribute__((address_space(3))) void*)(smem + 65536 + r * 4096 + tid * 16), 16, 0, 0);
    __syncthreads();   // drains vmcnt (incl. x loads); the ONLY barrier

    const unsigned short* LA  = (const unsigned short*)smem;    // AF, elements
    const unsigned short* WFg = frags + 32768;                  // WF in global (L2)
    const float* sBias = (const float*)(smem + 65536);

    // ---- convert xf (xr dies here; never live during the p-loop)
    Frag8 xf[2][4];
#pragma unroll
    for (int rb = 0; rb < 2; ++rb)
#pragma unroll
        for (int kc = 0; kc < 4; ++kc)
#pragma unroll
            for (int jp = 0; jp < 4; ++jp)
                xf[rb][kc].u4[jp] = pkbf(xr[(rb * 4 + kc) * 8 + 2 * jp],
                                         xr[(rb * 4 + kc) * 8 + 2 * jp + 1]);

    f32x16 acc[2][2];   // Y tiles: [cb over ac][nb2 over de]
#pragma unroll
    for (int a = 0; a < 2; ++a)
#pragma unroll
        for (int c = 0; c < 2; ++c)
#pragma unroll
            for (int e = 0; e < 16; ++e)
                acc[a][c][e] = 0.f;

    // ---- p-loop: AF from LDS, WF streamed from L2, MFMA + VALU repack.
    // No barriers, no cross-wave coupling.
#pragma unroll 1
    for (int p = 0; p < 8; ++p) {
        // WF loads issued first: 8 x global_load_dwordx4 (coalesced, L2-hit).
        // First use is after 8 step-A MFMAs + 2 repacks (~350cy) -> covered.
        Frag8 wf[2][4];
#pragma unroll
        for (int t = 0; t < 2; ++t)
#pragma unroll
            for (int kc = 0; kc < 4; ++kc)
                wf[t][kc].v = *(const bf16x8*)(WFg + p * 4096 + ((t * 4 + kc) * 64 + lane) * 8);
        Frag8 af[2][4];
#pragma unroll
        for (int t = 0; t < 2; ++t)
#pragma unroll
            for (int kc = 0; kc < 4; ++kc)
                af[t][kc].v = *(const bf16x8*)(LA + p * 4096 + ((t * 4 + kc) * 64 + lane) * 8);
#pragma unroll
        for (int rb = 0; rb < 2; ++rb) {       // rb: kl block (contraction of step B)
            Frag8 tb[2][2];                    // [cb][half]
#pragma unroll
            for (int cb = 0; cb < 2; ++cb) {   // cb: ac block
                // ---- Step A: T^T tile (kl rows rb*32.., ac cols cb*32..)
                f32x16 t;
#pragma unroll
                for (int e = 0; e < 16; ++e) t[e] = 0.f;
#pragma unroll
                for (int kc = 0; kc < 4; ++kc)
                    t = __builtin_amdgcn_mfma_f32_32x32x16_bf16(xf[rb][kc].v, af[cb][kc].v, t, 0, 0, 0);
                // ---- Repack C/D -> two step-B A-operand frags, in-register.
                unsigned int wd[8];
#pragma unroll
                for (int h = 0; h < 8; ++h) wd[h] = pkbf(t[2 * h], t[2 * h + 1]);
                auto s02 = __builtin_amdgcn_permlane32_swap(wd[0], wd[2], false, false);
                auto s13 = __builtin_amdgcn_permlane32_swap(wd[1], wd[3], false, false);
                auto s46 = __builtin_amdgcn_permlane32_swap(wd[4], wd[6], false, false);
                auto s57 = __builtin_amdgcn_permlane32_swap(wd[5], wd[7], false, false);
                tb[cb][0].u4[0] = s02[0]; tb[cb][0].u4[1] = s13[0];
                tb[cb][0].u4[2] = s02[1]; tb[cb][0].u4[3] = s13[1];
                tb[cb][1].u4[0] = s46[0]; tb[cb][1].u4[1] = s57[0];
                tb[cb][1].u4[2] = s46[1]; tb[cb][1].u4[3] = s57[1];
            }
            // ---- Step B: Y[ac][de] += T[ac][kl] * W[kl][de]  (wf first use)
#pragma unroll
            for (int cb = 0; cb < 2; ++cb) {
                acc[cb][0] = __builtin_amdgcn_mfma_f32_32x32x16_bf16(tb[cb][0].v, wf[0][2 * rb].v,     acc[cb][0], 0, 0, 0);
                acc[cb][0] = __builtin_amdgcn_mfma_f32_32x32x16_bf16(tb[cb][1].v, wf[0][2 * rb + 1].v, acc[cb][0], 0, 0, 0);
                acc[cb][1] = __builtin_amdgcn_mfma_f32_32x32x16_bf16(tb[cb][0].v, wf[1][2 * rb].v,     acc[cb][1], 0, 0, 0);
                acc[cb][1] = __builtin_amdgcn_mfma_f32_32x32x16_bf16(tb[cb][1].v, wf[1][2 * rb + 1].v, acc[cb][1], 0, 0, 0);
            }
        }
    }

    // ---- Epilogue: direct coalesced stores. C/D: col de = nb2*32+l31,
    // row ac = cb*32 + (r&3)+8*(r>>2)+4*hi. Bias from LDS (lgkm, not vmcnt).
    float* ob = out + ((size_t)b << 12);
#pragma unroll
    for (int cb = 0; cb < 2; ++cb)
#pragma unroll
        for (int nb2 = 0; nb2 < 2; ++nb2)
#pragma unroll
            for (int r = 0; r < 16; ++r) {
                int ac = cb * 32 + (r & 3) + 8 * (r >> 2) + 4 * hi;
                int o  = ac * 64 + nb2 * 32 + l31;
                ob[o] = acc[cb][nb2][r] + sBias[o];
            }
}

extern "C" void kernel_launch(void* const* d_in, const int* in_sizes, int n_in,
                              void* d_out, int out_size, void* d_ws, size_t ws_size,
                              hipStream_t stream) {
    const float* x    = (const float*)d_in[0];
    const float* F0   = (const float*)d_in[1];
    const float* F1   = (const float*)d_in[2];
    const float* F2   = (const float*)d_in[3];
    const float* F3   = (const float*)d_in[4];
    const float* CL   = (const float*)d_in[5];
    const float* CR   = (const float*)d_in[6];
    const float* bias = (const float*)d_in[7];
    float* out = (float*)d_out;
    unsigned short* frags = (unsigned short*)d_ws;   // 128 KB

    const int B = in_sizes[0] / 4096;   // 4096

    ht_precompute<<<16, 256, 0, stream>>>(F0, F1, F2, F3, CL, CR, frags);
    ht_main<<<B / 4, 256, 0, stream>>>(x, frags, bias, out);
}